// Round 7
// baseline (156.074 us; speedup 1.0000x reference)
//
#include <hip/hip_runtime.h>

// Performer causal linear attention, MI355X. Round 14 (resubmit — prior
// round failed on container acquisition, not kernel):
//  - feat_mfma: REVERT X staging to round-12's cooperative LDS path
//    (coalesced 1KB/wave float4 loads, Xhi/Xlo staged, fragments read
//    post-barrier; the block-wide conversion phase hides P-tile-0
//    global_load_lds latency) — round 13's per-wave direct X loads added
//    ~12us of stall (46->58us, VALU/MFMA busy-time constant).
//    KEEP round 13's wins: cvt_pk conversions everywhere, V-in-reg,
//    inline kmax reduce, LPT dispatch order.
// b=2 h=8 n=4096 d=64 r=256 e=64, chunk=64.

typedef unsigned short ushort_t;
typedef __attribute__((ext_vector_type(8))) short bf16x8;
typedef __attribute__((ext_vector_type(4))) float f32x4;

#define KEPS 1e-4f
#define AEPS 1e-6f
#define NORMIZER 0.35355339059327373f   // 64^-0.25
#define RATIO 0.0625f                   // 256^-0.5

__device__ __forceinline__ ushort_t bf16r(float f) {   // RNE
  unsigned u = __float_as_uint(f);
  return (ushort_t)((u + 0x7fffu + ((u >> 16) & 1u)) >> 16);
}
__device__ __forceinline__ float ubf(ushort_t h) {
  return __uint_as_float((unsigned)h << 16);
}
// packed RNE: D[15:0]=bf16(lo), D[31:16]=bf16(hi)
__device__ __forceinline__ unsigned cvtpk(float lo, float hi) {
  unsigned r;
  asm("v_cvt_pk_bf16_f32 %0, %1, %2" : "=v"(r) : "v"(lo), "v"(hi));
  return r;
}
union U32V { unsigned u[4]; bf16x8 v; };

// ---------------------------------------------------------------------------
// K0: split P into bf16 hi/lo.
__global__ __launch_bounds__(256) void pconv_kernel(
    const float* __restrict__ P, ushort_t* __restrict__ Phi,
    ushort_t* __restrict__ Plo)
{
  int idx = blockIdx.x * 1024 + threadIdx.x;
  #pragma unroll
  for (int p = 0; p < 4; ++p) {
    int i = idx + p * 256;
    float x = P[i];
    ushort_t h = bf16r(x);
    Phi[i] = h;
    Plo[i] = bf16r(x - ubf(h));
  }
}

// ---------------------------------------------------------------------------
// Stage one 8 KB P-tile (64 rows x 8 chunks of 16 B) into linear LDS with
// source-side XOR swizzle: LDS chunk (row, c) receives global chunk
// (row, c ^ (row & 7)).
__device__ __forceinline__ void stage_ptile(const ushort_t* __restrict__ gt,
                                            ushort_t* lds0, int tid) {
  int wv = tid >> 6, lane = tid & 63;
  #pragma unroll
  for (int i = 0; i < 2; ++i) {
    int D = i * 256 + wv * 64 + lane;        // dest chunk 0..511
    int row = D >> 3, c3 = D & 7;
    int sc = (row << 3) | (c3 ^ (row & 7));
    __builtin_amdgcn_global_load_lds(
        (const __attribute__((address_space(1))) void*)(gt + sc * 8),
        (__attribute__((address_space(3))) void*)(lds0 + (i * 256 + wv * 64) * 8),
        16, 0, 0);
  }
}

// ---------------------------------------------------------------------------
// K1: feature map via MFMA + (K-branch) fused per-chunk sums.
// blocks 0..1023 -> K (long), 1024..2047 -> Q (short): LPT ordering.
__global__ __launch_bounds__(256, 4) void feat_mfma(
    const float* __restrict__ Q, const float* __restrict__ K,
    const float* __restrict__ V,
    const ushort_t* __restrict__ Phi, const ushort_t* __restrict__ Plo,
    ushort_t* __restrict__ qp, ushort_t* __restrict__ E,
    float* __restrict__ bmax,
    ushort_t* __restrict__ SE, float* __restrict__ zE,
    float* __restrict__ SV)
{
  __shared__ union {
    struct {
      ushort_t Xhi[64 * 72];     // 9216 B
      ushort_t Xlo[64 * 72];     // 9216 B
      ushort_t Pt[2][4096];      // 16384 B
    } s;                         // 34816 B
    ushort_t outb[64 * 268];     // 34304 B epilogue staging
    ushort_t Et[256 * 72];       // 36864 B K-branch transposed E
  } u;
  __shared__ float diagS[64];
  __shared__ float redm[4];

  int bid = blockIdx.x, tid = threadIdx.x;
  bool isK = bid < 1024;             // K first (longer blocks)
  int bc = bid;                      // chunk index for K-branch
  const float* X = isK ? K : Q;
  size_t rowbase = (size_t)(isK ? bid : bid - 1024) * 64;

  int lane = tid & 63, wv = tid >> 6;
  int n15 = lane & 15, quad = lane >> 4;

  // kick off tile 0 (quarter 0, hi) immediately
  stage_ptile(Phi, &u.s.Pt[0][0], tid);

  // K-branch: V loaded directly in transposed-fragment order.
  float vraw[16];
  if (isK) {
    #pragma unroll
    for (int ks = 0; ks < 2; ++ks)
      #pragma unroll
      for (int jj = 0; jj < 8; ++jj) {
        int pos = quad * 8 + 32 * ks + jj;
        vraw[ks * 8 + jj] = V[rowbase * 64 + (size_t)pos * 64 + 16 * wv + n15];
      }
  }

  // stage X -> hi/lo bf16 via cvt_pk (coalesced 1KB/wave loads);
  // diag via 16-lane shuffle reduce on fp32 regs.
  #pragma unroll
  for (int p = 0; p < 4; ++p) {
    int idx = tid + p * 256;
    int row = idx >> 4, c4 = idx & 15;
    float4 x = *(const float4*)&X[(rowbase + row) * 64 + c4 * 4];
    unsigned h0 = cvtpk(x.x, x.y);
    unsigned h1 = cvtpk(x.z, x.w);
    float r0 = x.x - __uint_as_float(h0 << 16);
    float r1 = x.y - __uint_as_float(h0 & 0xffff0000u);
    float r2 = x.z - __uint_as_float(h1 << 16);
    float r3 = x.w - __uint_as_float(h1 & 0xffff0000u);
    unsigned l0 = cvtpk(r0, r1);
    unsigned l1 = cvtpk(r2, r3);
    unsigned* ph = (unsigned*)&u.s.Xhi[row * 72 + c4 * 4];
    ph[0] = h0; ph[1] = h1;
    unsigned* pl = (unsigned*)&u.s.Xlo[row * 72 + c4 * 4];
    pl[0] = l0; pl[1] = l1;
    float ss = x.x * x.x + x.y * x.y + x.z * x.z + x.w * x.w;
    ss += __shfl_xor(ss, 1, 64); ss += __shfl_xor(ss, 2, 64);
    ss += __shfl_xor(ss, 4, 64); ss += __shfl_xor(ss, 8, 64);
    if ((tid & 15) == 0) diagS[row] = 0.0625f * ss;
  }

  // K-branch: aV fragments + V colsum -> SV, before the main loop.
  bf16x8 aV[2];
  if (isK) {
    float vsum = 0.f;
    #pragma unroll
    for (int ks = 0; ks < 2; ++ks) {
      U32V A;
      #pragma unroll
      for (int j2 = 0; j2 < 4; ++j2) {
        vsum += vraw[ks * 8 + 2 * j2] + vraw[ks * 8 + 2 * j2 + 1];
        A.u[j2] = cvtpk(vraw[ks * 8 + 2 * j2], vraw[ks * 8 + 2 * j2 + 1]);
      }
      aV[ks] = A.v;
    }
    vsum += __shfl_xor(vsum, 16, 64);
    vsum += __shfl_xor(vsum, 32, 64);
    if (quad == 0) SV[(size_t)bc * 64 + 16 * wv + n15] = vsum;
  }

  __syncthreads();   // X ready; full drain -> tile 0 staged for all waves

  // A-fragments (hi/lo) from LDS
  bf16x8 ah[2], al[2];
  #pragma unroll
  for (int ks = 0; ks < 2; ++ks) {
    int off = (16 * wv + n15) * 72 + quad * 8 + 32 * ks;
    ah[ks] = *(const bf16x8*)&u.s.Xhi[off];
    al[ks] = *(const bf16x8*)&u.s.Xlo[off];
  }

  f32x4 acc[16];
  #pragma unroll
  for (int tc = 0; tc < 16; ++tc) acc[tc] = f32x4{0.f, 0.f, 0.f, 0.f};

  // 8 tiles: t = 2*q4 + (0:hi, 1:lo). hi-tile: acc += ah*b + al*b;
  // lo-tile: acc += ah*b. One barrier per tile; stage t+1 before MFMAs.
  int buf = 0;
  #pragma unroll
  for (int t = 0; t < 8; ++t) {
    int q4 = t >> 1;
    bool isLo = t & 1;
    if (t) {
      asm volatile("s_waitcnt vmcnt(0)" ::: "memory");
      __builtin_amdgcn_s_barrier();
    }
    if (t < 7) {
      int tn = t + 1;
      const ushort_t* gt = ((tn & 1) ? Plo : Phi) + (size_t)(tn >> 1) * 4096;
      stage_ptile(gt, &u.s.Pt[buf ^ 1][0], tid);
    }
    #pragma unroll
    for (int tcl = 0; tcl < 4; ++tcl) {
      f32x4 a = acc[q4 * 4 + tcl];
      #pragma unroll
      for (int ks = 0; ks < 2; ++ks) {
        int jr = 16 * tcl + n15;
        int rc = (quad + 4 * ks) ^ (n15 & 7);
        bf16x8 b = *(const bf16x8*)&u.s.Pt[buf][jr * 64 + rc * 8];
        a = __builtin_amdgcn_mfma_f32_16x16x32_bf16(ah[ks], b, a, 0, 0, 0);
        if (!isLo)
          a = __builtin_amdgcn_mfma_f32_16x16x32_bf16(al[ks], b, a, 0, 0, 0);
      }
      acc[q4 * 4 + tcl] = a;
    }
    buf ^= 1;
  }

  // C/D: row = 16*wv + quad*4 + r, col = 16*tc + n15
  float dg[4];
  #pragma unroll
  for (int r = 0; r < 4; ++r) dg[r] = diagS[16 * wv + quad * 4 + r];

  float sub[4];
  if (!isK) {
    #pragma unroll
    for (int r = 0; r < 4; ++r) {
      float mx = -3.0e38f;
      #pragma unroll
      for (int tc = 0; tc < 16; ++tc) mx = fmaxf(mx, acc[tc][r]);
      #pragma unroll
      for (int s = 1; s < 16; s <<= 1) mx = fmaxf(mx, __shfl_xor(mx, s, 64));
      sub[r] = dg[r] + NORMIZER * mx;
    }
  } else {
    float bm = -3.0e38f;
    #pragma unroll
    for (int tc = 0; tc < 16; ++tc)
      #pragma unroll
      for (int r = 0; r < 4; ++r) bm = fmaxf(bm, acc[tc][r]);
    #pragma unroll
    for (int s = 1; s < 64; s <<= 1) bm = fmaxf(bm, __shfl_xor(bm, s, 64));
    if (lane == 0) redm[wv] = bm;
    #pragma unroll
    for (int r = 0; r < 4; ++r) sub[r] = dg[r];
  }

  // single-pass epilogue through outb (aliases dead X/P LDS).
  // packed pairs via cvt_pk; hp kept for the K-branch Et build.
  unsigned hp[16][2];
  __syncthreads();   // all tile + fragment reads done; union reusable
  ushort_t* dst = (isK ? E : qp) + rowbase * 256;
  #pragma unroll
  for (int tc = 0; tc < 16; ++tc) {
    #pragma unroll
    for (int rp = 0; rp < 2; ++rp) {
      float e0 = __expf(NORMIZER * acc[tc][2 * rp]     - sub[2 * rp]);
      float e1 = __expf(NORMIZER * acc[tc][2 * rp + 1] - sub[2 * rp + 1]);
      float v0 = isK ? e0 : RATIO * (e0 + KEPS);
      float v1 = isK ? e1 : RATIO * (e1 + KEPS);
      unsigned pk = cvtpk(v0, v1);
      hp[tc][rp] = pk;
      int row = 16 * wv + quad * 4 + 2 * rp;
      u.outb[row * 268 + 16 * tc + n15] = (ushort_t)pk;
      u.outb[(row + 1) * 268 + 16 * tc + n15] = (ushort_t)(pk >> 16);
    }
  }
  __syncthreads();
  #pragma unroll
  for (int p = 0; p < 8; ++p) {
    int g = (tid + p * 256) * 8;
    int row = g >> 8, c0 = g & 255;
    bf16x8 v0 = *(const bf16x8*)&u.outb[row * 268 + c0];
    *(bf16x8*)&dst[row * 256 + c0] = v0;
  }

  if (isK && tid == 0) {
    float m4 = fmaxf(fmaxf(redm[0], redm[1]), fmaxf(redm[2], redm[3]));
    bmax[bc] = NORMIZER * m4;   // plain store, no contention
  }

  if (!isK) return;

  // ======================= fused chunksum (K-branch) =======================
  __syncthreads();   // all outb reads for the E store done; union reusable

  // Et build straight from the packed rounded E values:
  // Et[j*72 + ((pos + 8*((j>>3)&7)) & 63)] = E[pos][j], pos = 16wv+quad*4+r
  #pragma unroll
  for (int tc = 0; tc < 16; ++tc) {
    int j = 16 * tc + n15;
    int rot = 8 * ((j >> 3) & 7);
    int pw = (16 * wv + quad * 4 + rot) & 63;
    ushort4 w4;
    w4.x = (ushort_t)(hp[tc][0] & 0xffffu);
    w4.y = (ushort_t)(hp[tc][0] >> 16);
    w4.z = (ushort_t)(hp[tc][1] & 0xffffu);
    w4.w = (ushort_t)(hp[tc][1] >> 16);
    *(ushort4*)&u.Et[j * 72 + pw] = w4;
  }
  __syncthreads();

  {
    float s = 0.f;
    #pragma unroll
    for (int m8 = 0; m8 < 8; ++m8) {
      bf16x8 r8 = *(const bf16x8*)&u.Et[tid * 72 + m8 * 8];
      #pragma unroll
      for (int x = 0; x < 8; ++x) s += ubf((ushort_t)r8[x]);
    }
    zE[(size_t)bc * 256 + tid] = s;
  }

  f32x4 acc2[16];
  #pragma unroll
  for (int tc = 0; tc < 16; ++tc) {
    int j = 16 * tc + n15;
    int rot = 8 * ((j >> 3) & 7);
    f32x4 a = {0.f, 0.f, 0.f, 0.f};
    #pragma unroll
    for (int ks = 0; ks < 2; ++ks) {
      int pr = (quad * 8 + 32 * ks + rot) & 63;
      bf16x8 b = *(const bf16x8*)&u.Et[j * 72 + pr];
      a = __builtin_amdgcn_mfma_f32_16x16x32_bf16(aV[ks], b, a, 0, 0, 0);
    }
    acc2[tc] = a;
  }
  __syncthreads();   // Et reads done; reuse outb for SE staging

  #pragma unroll
  for (int tc = 0; tc < 16; ++tc)
    #pragma unroll
    for (int rp = 0; rp < 2; ++rp) {
      unsigned pk = cvtpk(acc2[tc][2 * rp], acc2[tc][2 * rp + 1]);
      int e0 = 16 * wv + quad * 4 + 2 * rp;
      u.outb[e0 * 268 + 16 * tc + n15] = (ushort_t)pk;
      u.outb[(e0 + 1) * 268 + 16 * tc + n15] = (ushort_t)(pk >> 16);
    }
  __syncthreads();
  ushort_t* sdst = SE + rowbase * 256;
  #pragma unroll
  for (int p = 0; p < 8; ++p) {
    int g = (tid + p * 256) * 8;
    int e = g >> 8, j0 = g & 255;
    bf16x8 v0 = *(const bf16x8*)&u.outb[e * 268 + j0];
    *(bf16x8*)&sdst[e * 256 + j0] = v0;
  }
}

// ---------------------------------------------------------------------------
// K3: exclusive prefix over 64 chunks per bh, applying kp affine correction.
// kmax reduced inline from bmax[1024] (4 KB, L3-resident).
__global__ __launch_bounds__(256) void prefix_kernel(
    ushort_t* __restrict__ S, float* __restrict__ zE,
    const float* __restrict__ SV, const float* __restrict__ bmax)
{
  __shared__ float redk[4];
  int tid = threadIdx.x;
  {
    float bm = fmaxf(fmaxf(bmax[tid], bmax[tid + 256]),
                     fmaxf(bmax[tid + 512], bmax[tid + 768]));
    #pragma unroll
    for (int s = 1; s < 64; s <<= 1) bm = fmaxf(bm, __shfl_xor(bm, s, 64));
    if ((tid & 63) == 0) redk[tid >> 6] = bm;
  }
  __syncthreads();
  float m = fmaxf(fmaxf(redk[0], redk[1]), fmaxf(redk[2], redk[3]));

  int b = blockIdx.x;
  float c1 = RATIO * __expf(-m);
  const float c0 = RATIO * KEPS;
  if (b < 1024) {
    int flat = b * 256 + tid;
    int bh = flat >> 14;
    int idx = flat & 16383;
    int e = idx >> 8;
    size_t base = (size_t)bh * 1048576 + idx;
    const float* svp = SV + (size_t)bh * 4096 + e;
    float runE = 0.f, runV = 0.f;
    for (int cc = 0; cc < 64; cc += 8) {
      ushort_t t[8]; float sv[8];
      #pragma unroll
      for (int u2 = 0; u2 < 8; ++u2) {
        t[u2] = S[base + (size_t)(cc + u2) * 16384];
        sv[u2] = svp[(size_t)(cc + u2) * 64];
      }
      #pragma unroll
      for (int u2 = 0; u2 < 8; ++u2) {
        S[base + (size_t)(cc + u2) * 16384] = bf16r(c1 * runE + c0 * runV);
        runE += ubf(t[u2]);
        runV += sv[u2];
      }
    }
  } else {
    int bh = b - 1024;
    int j = tid;
    size_t base = (size_t)bh * 16384 + j;
    float run = 0.f;
    for (int cc = 0; cc < 64; cc += 8) {
      float t[8];
      #pragma unroll
      for (int u2 = 0; u2 < 8; ++u2)
        t[u2] = zE[base + (size_t)(cc + u2) * 256];
      #pragma unroll
      for (int u2 = 0; u2 < 8; ++u2) {
        zE[base + (size_t)(cc + u2) * 256] = run;
        run += c1 * t[u2] + 64.0f * c0;
      }
    }
  }
}

// ---------------------------------------------------------------------------
// Stage one 8 KB B-tile (16 rows x 512 B) global->LDS with source-side XOR
// swizzle at 16B-chunk granularity (32 chunks/row).
__device__ __forceinline__ void stage_tile(const ushort_t* __restrict__ gt,
                                           ushort_t* lds0, int tid, int wv) {
  #pragma unroll
  for (int i = 0; i < 2; ++i) {
    int D = i * 256 + tid;             // dest chunk index 0..511
    int row = D >> 5, cl = D & 31;
    int sc = (row << 5) | (cl ^ (row & 7));
    __builtin_amdgcn_global_load_lds(
        (const __attribute__((address_space(1))) void*)(gt + sc * 8),
        (__attribute__((address_space(3))) void*)(lds0 + (i * 256 + wv * 64) * 8),
        16, 0, 0);
  }
}

// ---------------------------------------------------------------------------
// K4: fused MFMA scores + denominator + output. E/S tiles staged once per
// block in LDS (double-buffered global_load_lds), shared by all 4 waves.
__global__ __launch_bounds__(256) void fused_mfma(
    const ushort_t* __restrict__ qp, const ushort_t* __restrict__ E,
    const float* __restrict__ bmax, const float* __restrict__ Z,
    const ushort_t* __restrict__ S, const float* __restrict__ V,
    float* __restrict__ out)
{
  __shared__ ushort_t As[64 * 72];
  __shared__ ushort_t Vt[64 * 72];
  __shared__ ushort_t Bst[2][4096];     // 2 x 8 KB staged B tiles (swizzled)
  __shared__ float zv[256];
  __shared__ float qsumS[64];
  __shared__ float dqS[64];
  __shared__ float redk[4];

  int bc = blockIdx.x, tid = threadIdx.x;
  int lane = tid & 63, wv = tid >> 6;
  int n15 = lane & 15, quad = lane >> 4;
  const float c0 = RATIO * KEPS;
  size_t base = (size_t)bc * 16384;

  {
    float bm = fmaxf(fmaxf(bmax[tid], bmax[tid + 256]),
                     fmaxf(bmax[tid + 512], bmax[tid + 768]));
    #pragma unroll
    for (int s = 1; s < 64; s <<= 1) bm = fmaxf(bm, __shfl_xor(bm, s, 64));
    if (lane == 0) redk[wv] = bm;
  }
  zv[tid] = Z[(size_t)bc * 256 + tid] + AEPS;
  #pragma unroll
  for (int p = 0; p < 16; ++p) {
    int idx = tid + p * 256;
    int t = idx >> 6, e = idx & 63;
    Vt[e * 72 + t] = bf16r(V[(size_t)bc * 4096 + idx]);
  }
  __syncthreads();
  float m = fmaxf(fmaxf(redk[0], redk[1]), fmaxf(redk[2], redk[3]));
  float c1 = RATIO * __expf(-m);

  // kick off tile 0 (E rows 0..15) while we do the qsum/dq VALU work
  stage_tile(E + base, &Bst[0][0], tid, wv);

  bf16x8 aQ[8];
  #pragma unroll
  for (int ks = 0; ks < 8; ++ks)
    aQ[ks] = *(const bf16x8*)&qp[base + (size_t)(16 * wv + n15) * 256 + quad * 8 + 32 * ks];

  float qsum = 0.f, dq = 0.f;
  #pragma unroll
  for (int ks = 0; ks < 8; ++ks)
    #pragma unroll
    for (int j = 0; j < 8; ++j) {
      float qv = ubf((ushort_t)aQ[ks][j]);
      qsum += qv;
      dq += qv * zv[quad * 8 + 32 * ks + j];
    }
  qsum += __shfl_xor(qsum, 16, 64); qsum += __shfl_xor(qsum, 32, 64);
  dq   += __shfl_xor(dq, 16, 64);   dq   += __shfl_xor(dq, 32, 64);
  if (quad == 0) { qsumS[16 * wv + n15] = qsum; dqS[16 * wv + n15] = dq; }

  // 8 tiles: t=0..3 -> phase A (G = Qp*E^T, causal mask, As, rowsum);
  //          t=4..7 -> phase C (out = Qp*Sp + A_sc*Vt).
  float rs[4] = {0.f, 0.f, 0.f, 0.f};
  float dinv[4] = {0.f, 0.f, 0.f, 0.f};

  #pragma unroll
  for (int t = 0; t < 8; ++t) {
    asm volatile("s_waitcnt vmcnt(0)" ::: "memory");
    __builtin_amdgcn_s_barrier();
    if (t < 7) {
      const ushort_t* gt = (t < 3) ? (E + base + (size_t)(t + 1) * 4096)
                                   : (S + base + (size_t)(t - 3) * 4096);
      stage_tile(gt, &Bst[(t + 1) & 1][0], tid, wv);
    }

    bf16x8 bf[8];
    #pragma unroll
    for (int ks = 0; ks < 8; ++ks) {
      int rc = (4 * ks + quad) ^ (n15 & 7);
      bf[ks] = *(const bf16x8*)&Bst[t & 1][(n15 * 32 + rc) * 8];
    }
    f32x4 g = {0.f, 0.f, 0.f, 0.f};
    #pragma unroll
    for (int ks = 0; ks < 8; ++ks)
      g = __builtin_amdgcn_mfma_f32_16x16x32_bf16(aQ[ks], bf[ks], g, 0, 0, 0);

    if (t < 4) {
      int tc = t;
      #pragma unroll
      for (int rp = 0; rp < 2; ++rp) {
        int i0 = 16 * wv + quad * 4 + 2 * rp;
        int tt = 16 * tc + n15;
        float v0 = (tt <= i0)     ? (c1 * g[2 * rp]     + c0 * qsumS[i0])     : 0.f;
        float v1 = (tt <= i0 + 1) ? (c1 * g[2 * rp + 1] + c0 * qsumS[i0 + 1]) : 0.f;
        unsigned pk = cvtpk(v0, v1);
        As[i0 * 72 + tt] = (ushort_t)pk;
        As[(i0 + 1) * 72 + tt] = (ushort_t)(pk >> 16);
        rs[2 * rp] += v0;
        rs[2 * rp + 1] += v1;
      }
      if (t == 3) {
        #pragma unroll
        for (int r = 0; r < 4; ++r) {
          float v2 = rs[r];
          #pragma unroll
          for (int s = 1; s < 16; s <<= 1) v2 += __shfl_xor(v2, s, 64);
          int i = 16 * wv + quad * 4 + r;
          dinv[r] = 1.f / (dqS[i] + v2);
        }
      }
    } else {
      int ec = t - 4;
      f32x4 o = g;
      #pragma unroll
      for (int ks = 0; ks < 2; ++ks) {
        bf16x8 a2 = *(const bf16x8*)&As[(16 * wv + n15) * 72 + quad * 8 + 32 * ks];
        bf16x8 b2 = *(const bf16x8*)&Vt[(16 * ec + n15) * 72 + quad * 8 + 32 * ks];
        o = __builtin_amdgcn_mfma_f32_16x16x32_bf16(a2, b2, o, 0, 0, 0);
      }
      #pragma unroll
      for (int r = 0; r < 4; ++r) {
        int i = 16 * wv + quad * 4 + r;
        out[(size_t)bc * 4096 + (size_t)i * 64 + 16 * ec + n15] = o[r] * dinv[r];
      }
    }
  }
}

// ---------------------------------------------------------------------------
extern "C" void kernel_launch(void* const* d_in, const int* in_sizes, int n_in,
                              void* d_out, int out_size, void* d_ws, size_t ws_size,
                              hipStream_t stream)
{
  const float* q = (const float*)d_in[0];
  const float* k = (const float*)d_in[1];
  const float* v = (const float*)d_in[2];
  const float* P = (const float*)d_in[3];
  float* out = (float*)d_out;

  ushort_t* qp  = (ushort_t*)d_ws;
  ushort_t* E   = qp + 16777216;
  ushort_t* S   = E + 16777216;                 // SE then combined in place
  float*    zE  = (float*)(S + 16777216);       // 262144 floats
  float*    SV  = zE + 262144;                  // 65536 floats
  ushort_t* Phi = (ushort_t*)(SV + 65536);
  ushort_t* Plo = Phi + 16384;
  float*    bmax = (float*)(Plo + 16384);       // 1024 floats

  pconv_kernel<<<16, 256, 0, stream>>>(P, Phi, Plo);
  feat_mfma<<<2048, 256, 0, stream>>>(q, k, v, Phi, Plo, qp, E, bmax,
                                      S, zE, SV);
  prefix_kernel<<<1040, 256, 0, stream>>>(S, zE, SV, bmax);
  fused_mfma<<<1024, 256, 0, stream>>>(qp, E, bmax, zE, S, v, out);
}

// Round 8
// 148.990 us; speedup vs baseline: 1.0475x; 1.0475x over previous
//
#include <hip/hip_runtime.h>

// Performer causal linear attention, MI355X. Round 15:
//  - Q-feature computation MERGED into fused_mfma: feat is now K-only
//    (1024 uniform blocks); qp array eliminated (64 MB of traffic).
//    fused computes Qp itself (same P-tile MFMA loop through Bst, same
//    RNE rounding -> bit-identical aQ), redistributes C->A layout via a
//    half-width (128-col x2) LDS pass. P-loop tile-7 slot stages E-tile-0
//    so phase 2 starts with its buffer already in flight.
//    LDS 36.6 KB -> 4 blocks/CU, __launch_bounds__(256,4).
// b=2 h=8 n=4096 d=64 r=256 e=64, chunk=64.

typedef unsigned short ushort_t;
typedef __attribute__((ext_vector_type(8))) short bf16x8;
typedef __attribute__((ext_vector_type(4))) float f32x4;

#define KEPS 1e-4f
#define AEPS 1e-6f
#define NORMIZER 0.35355339059327373f   // 64^-0.25
#define RATIO 0.0625f                   // 256^-0.5

__device__ __forceinline__ ushort_t bf16r(float f) {   // RNE
  unsigned u = __float_as_uint(f);
  return (ushort_t)((u + 0x7fffu + ((u >> 16) & 1u)) >> 16);
}
__device__ __forceinline__ float ubf(ushort_t h) {
  return __uint_as_float((unsigned)h << 16);
}
// packed RNE: D[15:0]=bf16(lo), D[31:16]=bf16(hi)
__device__ __forceinline__ unsigned cvtpk(float lo, float hi) {
  unsigned r;
  asm("v_cvt_pk_bf16_f32 %0, %1, %2" : "=v"(r) : "v"(lo), "v"(hi));
  return r;
}
union U32V { unsigned u[4]; bf16x8 v; };

// ---------------------------------------------------------------------------
// K0: split P into bf16 hi/lo.
__global__ __launch_bounds__(256) void pconv_kernel(
    const float* __restrict__ P, ushort_t* __restrict__ Phi,
    ushort_t* __restrict__ Plo)
{
  int idx = blockIdx.x * 1024 + threadIdx.x;
  #pragma unroll
  for (int p = 0; p < 4; ++p) {
    int i = idx + p * 256;
    float x = P[i];
    ushort_t h = bf16r(x);
    Phi[i] = h;
    Plo[i] = bf16r(x - ubf(h));
  }
}

// ---------------------------------------------------------------------------
// Stage one 8 KB P-tile (64 rows x 8 chunks of 16 B) into linear LDS with
// source-side XOR swizzle: LDS chunk (row, c) receives global chunk
// (row, c ^ (row & 7)).
__device__ __forceinline__ void stage_ptile(const ushort_t* __restrict__ gt,
                                            ushort_t* lds0, int tid) {
  int wv = tid >> 6, lane = tid & 63;
  #pragma unroll
  for (int i = 0; i < 2; ++i) {
    int D = i * 256 + wv * 64 + lane;        // dest chunk 0..511
    int row = D >> 3, c3 = D & 7;
    int sc = (row << 3) | (c3 ^ (row & 7));
    __builtin_amdgcn_global_load_lds(
        (const __attribute__((address_space(1))) void*)(gt + sc * 8),
        (__attribute__((address_space(3))) void*)(lds0 + (i * 256 + wv * 64) * 8),
        16, 0, 0);
  }
}

// ---------------------------------------------------------------------------
// Stage one 8 KB B-tile (16 rows x 512 B) global->LDS with source-side XOR
// swizzle at 16B-chunk granularity (32 chunks/row).
__device__ __forceinline__ void stage_tile(const ushort_t* __restrict__ gt,
                                           ushort_t* lds0, int tid, int wv) {
  #pragma unroll
  for (int i = 0; i < 2; ++i) {
    int D = i * 256 + tid;             // dest chunk index 0..511
    int row = D >> 5, cl = D & 31;
    int sc = (row << 5) | (cl ^ (row & 7));
    __builtin_amdgcn_global_load_lds(
        (const __attribute__((address_space(1))) void*)(gt + sc * 8),
        (__attribute__((address_space(3))) void*)(lds0 + (i * 256 + wv * 64) * 8),
        16, 0, 0);
  }
}

// ---------------------------------------------------------------------------
// K1: K feature map via MFMA + fused per-chunk sums. 1024 uniform blocks.
__global__ __launch_bounds__(256, 4) void feat_mfma(
    const float* __restrict__ K, const float* __restrict__ V,
    const ushort_t* __restrict__ Phi, const ushort_t* __restrict__ Plo,
    ushort_t* __restrict__ E, float* __restrict__ bmax,
    ushort_t* __restrict__ SE, float* __restrict__ zE,
    float* __restrict__ SV)
{
  __shared__ union {
    struct {
      ushort_t Xhi[64 * 72];     // 9216 B
      ushort_t Xlo[64 * 72];     // 9216 B
      ushort_t Pt[2][4096];      // 16384 B
    } s;                         // 34816 B
    ushort_t outb[64 * 268];     // 34304 B epilogue staging
    ushort_t Et[256 * 72];       // 36864 B transposed E
  } u;
  __shared__ float diagS[64];
  __shared__ float redm[4];

  int bc = blockIdx.x, tid = threadIdx.x;
  size_t rowbase = (size_t)bc * 64;

  int lane = tid & 63, wv = tid >> 6;
  int n15 = lane & 15, quad = lane >> 4;

  // kick off tile 0 (quarter 0, hi) immediately
  stage_ptile(Phi, &u.s.Pt[0][0], tid);

  // V loaded directly in transposed-fragment order.
  float vraw[16];
  #pragma unroll
  for (int ks = 0; ks < 2; ++ks)
    #pragma unroll
    for (int jj = 0; jj < 8; ++jj) {
      int pos = quad * 8 + 32 * ks + jj;
      vraw[ks * 8 + jj] = V[rowbase * 64 + (size_t)pos * 64 + 16 * wv + n15];
    }

  // stage K -> hi/lo bf16 via cvt_pk (coalesced 1KB/wave loads);
  // diag via 16-lane shuffle reduce on fp32 regs.
  #pragma unroll
  for (int p = 0; p < 4; ++p) {
    int idx = tid + p * 256;
    int row = idx >> 4, c4 = idx & 15;
    float4 x = *(const float4*)&K[(rowbase + row) * 64 + c4 * 4];
    unsigned h0 = cvtpk(x.x, x.y);
    unsigned h1 = cvtpk(x.z, x.w);
    float r0 = x.x - __uint_as_float(h0 << 16);
    float r1 = x.y - __uint_as_float(h0 & 0xffff0000u);
    float r2 = x.z - __uint_as_float(h1 << 16);
    float r3 = x.w - __uint_as_float(h1 & 0xffff0000u);
    unsigned l0 = cvtpk(r0, r1);
    unsigned l1 = cvtpk(r2, r3);
    unsigned* ph = (unsigned*)&u.s.Xhi[row * 72 + c4 * 4];
    ph[0] = h0; ph[1] = h1;
    unsigned* pl = (unsigned*)&u.s.Xlo[row * 72 + c4 * 4];
    pl[0] = l0; pl[1] = l1;
    float ss = x.x * x.x + x.y * x.y + x.z * x.z + x.w * x.w;
    ss += __shfl_xor(ss, 1, 64); ss += __shfl_xor(ss, 2, 64);
    ss += __shfl_xor(ss, 4, 64); ss += __shfl_xor(ss, 8, 64);
    if ((tid & 15) == 0) diagS[row] = 0.0625f * ss;
  }

  // aV fragments + V colsum -> SV, before the main loop.
  bf16x8 aV[2];
  {
    float vsum = 0.f;
    #pragma unroll
    for (int ks = 0; ks < 2; ++ks) {
      U32V A;
      #pragma unroll
      for (int j2 = 0; j2 < 4; ++j2) {
        vsum += vraw[ks * 8 + 2 * j2] + vraw[ks * 8 + 2 * j2 + 1];
        A.u[j2] = cvtpk(vraw[ks * 8 + 2 * j2], vraw[ks * 8 + 2 * j2 + 1]);
      }
      aV[ks] = A.v;
    }
    vsum += __shfl_xor(vsum, 16, 64);
    vsum += __shfl_xor(vsum, 32, 64);
    if (quad == 0) SV[(size_t)bc * 64 + 16 * wv + n15] = vsum;
  }

  __syncthreads();   // X ready; full drain -> tile 0 staged for all waves

  bf16x8 ah[2], al[2];
  #pragma unroll
  for (int ks = 0; ks < 2; ++ks) {
    int off = (16 * wv + n15) * 72 + quad * 8 + 32 * ks;
    ah[ks] = *(const bf16x8*)&u.s.Xhi[off];
    al[ks] = *(const bf16x8*)&u.s.Xlo[off];
  }

  f32x4 acc[16];
  #pragma unroll
  for (int tc = 0; tc < 16; ++tc) acc[tc] = f32x4{0.f, 0.f, 0.f, 0.f};

  int buf = 0;
  #pragma unroll
  for (int t = 0; t < 8; ++t) {
    int q4 = t >> 1;
    bool isLo = t & 1;
    if (t) {
      asm volatile("s_waitcnt vmcnt(0)" ::: "memory");
      __builtin_amdgcn_s_barrier();
    }
    if (t < 7) {
      int tn = t + 1;
      const ushort_t* gt = ((tn & 1) ? Plo : Phi) + (size_t)(tn >> 1) * 4096;
      stage_ptile(gt, &u.s.Pt[buf ^ 1][0], tid);
    }
    #pragma unroll
    for (int tcl = 0; tcl < 4; ++tcl) {
      f32x4 a = acc[q4 * 4 + tcl];
      #pragma unroll
      for (int ks = 0; ks < 2; ++ks) {
        int jr = 16 * tcl + n15;
        int rc = (quad + 4 * ks) ^ (n15 & 7);
        bf16x8 b = *(const bf16x8*)&u.s.Pt[buf][jr * 64 + rc * 8];
        a = __builtin_amdgcn_mfma_f32_16x16x32_bf16(ah[ks], b, a, 0, 0, 0);
        if (!isLo)
          a = __builtin_amdgcn_mfma_f32_16x16x32_bf16(al[ks], b, a, 0, 0, 0);
      }
      acc[q4 * 4 + tcl] = a;
    }
    buf ^= 1;
  }

  // C/D: row = 16*wv + quad*4 + r, col = 16*tc + n15
  float dg[4];
  #pragma unroll
  for (int r = 0; r < 4; ++r) dg[r] = diagS[16 * wv + quad * 4 + r];

  {
    float bm = -3.0e38f;
    #pragma unroll
    for (int tc = 0; tc < 16; ++tc)
      #pragma unroll
      for (int r = 0; r < 4; ++r) bm = fmaxf(bm, acc[tc][r]);
    #pragma unroll
    for (int s = 1; s < 64; s <<= 1) bm = fmaxf(bm, __shfl_xor(bm, s, 64));
    if (lane == 0) redm[wv] = bm;
  }

  // single-pass epilogue through outb (aliases dead X/P LDS).
  // packed pairs via cvt_pk; hp kept for the Et build.
  unsigned hp[16][2];
  __syncthreads();   // all tile + fragment reads done; union reusable
  ushort_t* dst = E + rowbase * 256;
  #pragma unroll
  for (int tc = 0; tc < 16; ++tc) {
    #pragma unroll
    for (int rp = 0; rp < 2; ++rp) {
      float e0 = __expf(NORMIZER * acc[tc][2 * rp]     - dg[2 * rp]);
      float e1 = __expf(NORMIZER * acc[tc][2 * rp + 1] - dg[2 * rp + 1]);
      unsigned pk = cvtpk(e0, e1);
      hp[tc][rp] = pk;
      int row = 16 * wv + quad * 4 + 2 * rp;
      u.outb[row * 268 + 16 * tc + n15] = (ushort_t)pk;
      u.outb[(row + 1) * 268 + 16 * tc + n15] = (ushort_t)(pk >> 16);
    }
  }
  __syncthreads();
  #pragma unroll
  for (int p = 0; p < 8; ++p) {
    int g = (tid + p * 256) * 8;
    int row = g >> 8, c0 = g & 255;
    bf16x8 v0 = *(const bf16x8*)&u.outb[row * 268 + c0];
    *(bf16x8*)&dst[row * 256 + c0] = v0;
  }

  if (tid == 0) {
    float m4 = fmaxf(fmaxf(redm[0], redm[1]), fmaxf(redm[2], redm[3]));
    bmax[bc] = NORMIZER * m4;   // plain store, no contention
  }

  // ======================= fused chunksum =======================
  __syncthreads();   // all outb reads for the E store done; union reusable

  // Et build straight from the packed rounded E values:
  // Et[j*72 + ((pos + 8*((j>>3)&7)) & 63)] = E[pos][j], pos = 16wv+quad*4+r
  #pragma unroll
  for (int tc = 0; tc < 16; ++tc) {
    int j = 16 * tc + n15;
    int rot = 8 * ((j >> 3) & 7);
    int pw = (16 * wv + quad * 4 + rot) & 63;
    ushort4 w4;
    w4.x = (ushort_t)(hp[tc][0] & 0xffffu);
    w4.y = (ushort_t)(hp[tc][0] >> 16);
    w4.z = (ushort_t)(hp[tc][1] & 0xffffu);
    w4.w = (ushort_t)(hp[tc][1] >> 16);
    *(ushort4*)&u.Et[j * 72 + pw] = w4;
  }
  __syncthreads();

  {
    float s = 0.f;
    #pragma unroll
    for (int m8 = 0; m8 < 8; ++m8) {
      bf16x8 r8 = *(const bf16x8*)&u.Et[tid * 72 + m8 * 8];
      #pragma unroll
      for (int x = 0; x < 8; ++x) s += ubf((ushort_t)r8[x]);
    }
    zE[(size_t)bc * 256 + tid] = s;
  }

  f32x4 acc2[16];
  #pragma unroll
  for (int tc = 0; tc < 16; ++tc) {
    int j = 16 * tc + n15;
    int rot = 8 * ((j >> 3) & 7);
    f32x4 a = {0.f, 0.f, 0.f, 0.f};
    #pragma unroll
    for (int ks = 0; ks < 2; ++ks) {
      int pr = (quad * 8 + 32 * ks + rot) & 63;
      bf16x8 b = *(const bf16x8*)&u.Et[j * 72 + pr];
      a = __builtin_amdgcn_mfma_f32_16x16x32_bf16(aV[ks], b, a, 0, 0, 0);
    }
    acc2[tc] = a;
  }
  __syncthreads();   // Et reads done; reuse outb for SE staging

  #pragma unroll
  for (int tc = 0; tc < 16; ++tc)
    #pragma unroll
    for (int rp = 0; rp < 2; ++rp) {
      unsigned pk = cvtpk(acc2[tc][2 * rp], acc2[tc][2 * rp + 1]);
      int e0 = 16 * wv + quad * 4 + 2 * rp;
      u.outb[e0 * 268 + 16 * tc + n15] = (ushort_t)pk;
      u.outb[(e0 + 1) * 268 + 16 * tc + n15] = (ushort_t)(pk >> 16);
    }
  __syncthreads();
  ushort_t* sdst = SE + rowbase * 256;
  #pragma unroll
  for (int p = 0; p < 8; ++p) {
    int g = (tid + p * 256) * 8;
    int e = g >> 8, j0 = g & 255;
    bf16x8 v0 = *(const bf16x8*)&u.outb[e * 268 + j0];
    *(bf16x8*)&sdst[e * 256 + j0] = v0;
  }
}

// ---------------------------------------------------------------------------
// K3: exclusive prefix over 64 chunks per bh, applying kp affine correction.
// kmax reduced inline from bmax[1024] (4 KB, L3-resident).
__global__ __launch_bounds__(256) void prefix_kernel(
    ushort_t* __restrict__ S, float* __restrict__ zE,
    const float* __restrict__ SV, const float* __restrict__ bmax)
{
  __shared__ float redk[4];
  int tid = threadIdx.x;
  {
    float bm = fmaxf(fmaxf(bmax[tid], bmax[tid + 256]),
                     fmaxf(bmax[tid + 512], bmax[tid + 768]));
    #pragma unroll
    for (int s = 1; s < 64; s <<= 1) bm = fmaxf(bm, __shfl_xor(bm, s, 64));
    if ((tid & 63) == 0) redk[tid >> 6] = bm;
  }
  __syncthreads();
  float m = fmaxf(fmaxf(redk[0], redk[1]), fmaxf(redk[2], redk[3]));

  int b = blockIdx.x;
  float c1 = RATIO * __expf(-m);
  const float c0 = RATIO * KEPS;
  if (b < 1024) {
    int flat = b * 256 + tid;
    int bh = flat >> 14;
    int idx = flat & 16383;
    int e = idx >> 8;
    size_t base = (size_t)bh * 1048576 + idx;
    const float* svp = SV + (size_t)bh * 4096 + e;
    float runE = 0.f, runV = 0.f;
    for (int cc = 0; cc < 64; cc += 8) {
      ushort_t t[8]; float sv[8];
      #pragma unroll
      for (int u2 = 0; u2 < 8; ++u2) {
        t[u2] = S[base + (size_t)(cc + u2) * 16384];
        sv[u2] = svp[(size_t)(cc + u2) * 64];
      }
      #pragma unroll
      for (int u2 = 0; u2 < 8; ++u2) {
        S[base + (size_t)(cc + u2) * 16384] = bf16r(c1 * runE + c0 * runV);
        runE += ubf(t[u2]);
        runV += sv[u2];
      }
    }
  } else {
    int bh = b - 1024;
    int j = tid;
    size_t base = (size_t)bh * 16384 + j;
    float run = 0.f;
    for (int cc = 0; cc < 64; cc += 8) {
      float t[8];
      #pragma unroll
      for (int u2 = 0; u2 < 8; ++u2)
        t[u2] = zE[base + (size_t)(cc + u2) * 256];
      #pragma unroll
      for (int u2 = 0; u2 < 8; ++u2) {
        zE[base + (size_t)(cc + u2) * 256] = run;
        run += c1 * t[u2] + 64.0f * c0;
      }
    }
  }
}

// ---------------------------------------------------------------------------
// K4: Qp feature map + fused MFMA scores + denominator + output.
// Phase 1: Qp = feature(Q) via P-tile loop through Bst; C->A redistribution
//          via half-width qpb LDS (2 x 128 cols).
// Phase 2: G = Qp*E^T (causal, As, rowsum) then out = Qp*Sp + A_sc*Vt.
__global__ __launch_bounds__(256, 4) void fused_mfma(
    const float* __restrict__ Q,
    const ushort_t* __restrict__ Phi, const ushort_t* __restrict__ Plo,
    const ushort_t* __restrict__ E, const float* __restrict__ bmax,
    const float* __restrict__ Z, const ushort_t* __restrict__ S,
    const float* __restrict__ V, float* __restrict__ out)
{
  __shared__ union {
    struct { ushort_t Xhi[64 * 72]; ushort_t Xlo[64 * 72]; } x;  // 18432 B
    ushort_t qpb[64 * 136];                                      // 17408 B
    struct { ushort_t As[64 * 72]; ushort_t Vt[64 * 72]; } c;    // 18432 B
  } u;
  __shared__ ushort_t Bst[2][4096];     // 16384 B staged tiles (P, then E/S)
  __shared__ float zv[256];
  __shared__ float qsumS[64];
  __shared__ float dqS[64];
  __shared__ float diagS[64];
  __shared__ float redk[4];

  int bc = blockIdx.x, tid = threadIdx.x;
  int lane = tid & 63, wv = tid >> 6;
  int n15 = lane & 15, quad = lane >> 4;
  const float c0 = RATIO * KEPS;
  size_t base = (size_t)bc * 16384;
  size_t rowbase = (size_t)bc * 64;

  // kick off P tile 0 (quarter 0, hi) immediately
  stage_ptile(Phi, &Bst[0][0], tid);

  {
    float bm = fmaxf(fmaxf(bmax[tid], bmax[tid + 256]),
                     fmaxf(bmax[tid + 512], bmax[tid + 768]));
    #pragma unroll
    for (int s = 1; s < 64; s <<= 1) bm = fmaxf(bm, __shfl_xor(bm, s, 64));
    if (lane == 0) redk[wv] = bm;
  }
  zv[tid] = Z[(size_t)bc * 256 + tid] + AEPS;

  // stage Q -> hi/lo bf16 via cvt_pk; diag via 16-lane shuffle reduce.
  #pragma unroll
  for (int p = 0; p < 4; ++p) {
    int idx = tid + p * 256;
    int row = idx >> 4, c4 = idx & 15;
    float4 x = *(const float4*)&Q[(rowbase + row) * 64 + c4 * 4];
    unsigned h0 = cvtpk(x.x, x.y);
    unsigned h1 = cvtpk(x.z, x.w);
    float r0 = x.x - __uint_as_float(h0 << 16);
    float r1 = x.y - __uint_as_float(h0 & 0xffff0000u);
    float r2 = x.z - __uint_as_float(h1 << 16);
    float r3 = x.w - __uint_as_float(h1 & 0xffff0000u);
    unsigned l0 = cvtpk(r0, r1);
    unsigned l1 = cvtpk(r2, r3);
    unsigned* ph = (unsigned*)&u.x.Xhi[row * 72 + c4 * 4];
    ph[0] = h0; ph[1] = h1;
    unsigned* pl = (unsigned*)&u.x.Xlo[row * 72 + c4 * 4];
    pl[0] = l0; pl[1] = l1;
    float ss = x.x * x.x + x.y * x.y + x.z * x.z + x.w * x.w;
    ss += __shfl_xor(ss, 1, 64); ss += __shfl_xor(ss, 2, 64);
    ss += __shfl_xor(ss, 4, 64); ss += __shfl_xor(ss, 8, 64);
    if ((tid & 15) == 0) diagS[row] = 0.0625f * ss;
  }
  __syncthreads();   // X ready; P tile 0 staged for all waves
  float m = fmaxf(fmaxf(redk[0], redk[1]), fmaxf(redk[2], redk[3]));
  float c1 = RATIO * __expf(-m);

  bf16x8 ah[2], al[2];
  #pragma unroll
  for (int ks = 0; ks < 2; ++ks) {
    int off = (16 * wv + n15) * 72 + quad * 8 + 32 * ks;
    ah[ks] = *(const bf16x8*)&u.x.Xhi[off];
    al[ks] = *(const bf16x8*)&u.x.Xlo[off];
  }

  f32x4 acc[16];
  #pragma unroll
  for (int tc = 0; tc < 16; ++tc) acc[tc] = f32x4{0.f, 0.f, 0.f, 0.f};

  // ---- phase 1: Qp main loop (8 P tiles through Bst) ----
  int buf = 0;
  #pragma unroll
  for (int t = 0; t < 8; ++t) {
    int q4 = t >> 1;
    bool isLo = t & 1;
    if (t) {
      asm volatile("s_waitcnt vmcnt(0)" ::: "memory");
      __builtin_amdgcn_s_barrier();
    }
    if (t < 7) {
      int tn = t + 1;
      const ushort_t* gt = ((tn & 1) ? Plo : Phi) + (size_t)(tn >> 1) * 4096;
      stage_ptile(gt, &Bst[buf ^ 1][0], tid);
    } else {
      stage_tile(E + base, &Bst[buf ^ 1][0], tid, wv);   // E tile 0
    }
    #pragma unroll
    for (int tcl = 0; tcl < 4; ++tcl) {
      f32x4 a = acc[q4 * 4 + tcl];
      #pragma unroll
      for (int ks = 0; ks < 2; ++ks) {
        int jr = 16 * tcl + n15;
        int rc = (quad + 4 * ks) ^ (n15 & 7);
        bf16x8 b = *(const bf16x8*)&Bst[buf][jr * 64 + rc * 8];
        a = __builtin_amdgcn_mfma_f32_16x16x32_bf16(ah[ks], b, a, 0, 0, 0);
        if (!isLo)
          a = __builtin_amdgcn_mfma_f32_16x16x32_bf16(al[ks], b, a, 0, 0, 0);
      }
      acc[q4 * 4 + tcl] = a;
    }
    buf ^= 1;
  }
  // after 8 iterations buf == 0; E tile 0 sits in Bst[0].

  // row-max (is_query) + sub
  float sub[4];
  {
    float dg[4];
    #pragma unroll
    for (int r = 0; r < 4; ++r) dg[r] = diagS[16 * wv + quad * 4 + r];
    #pragma unroll
    for (int r = 0; r < 4; ++r) {
      float mx = -3.0e38f;
      #pragma unroll
      for (int tc = 0; tc < 16; ++tc) mx = fmaxf(mx, acc[tc][r]);
      #pragma unroll
      for (int s = 1; s < 16; s <<= 1) mx = fmaxf(mx, __shfl_xor(mx, s, 64));
      sub[r] = dg[r] + NORMIZER * mx;
    }
  }

  // ---- qp values + C->A redistribution, 2 half-width passes ----
  float qsum = 0.f, dq = 0.f;
  bf16x8 aQ[8];
  #pragma unroll
  for (int h = 0; h < 2; ++h) {
    if (h) __syncthreads();          // half-0 reads done before overwrite
    #pragma unroll
    for (int tcl = 0; tcl < 8; ++tcl) {
      int tc = 8 * h + tcl;
      #pragma unroll
      for (int rp = 0; rp < 2; ++rp) {
        float e0 = __expf(NORMIZER * acc[tc][2 * rp]     - sub[2 * rp]);
        float e1 = __expf(NORMIZER * acc[tc][2 * rp + 1] - sub[2 * rp + 1]);
        unsigned pk = cvtpk(RATIO * (e0 + KEPS), RATIO * (e1 + KEPS));
        int i0 = 16 * wv + quad * 4 + 2 * rp;
        int cp = 16 * tcl + n15;
        u.qpb[i0 * 136 + cp] = (ushort_t)pk;
        u.qpb[(i0 + 1) * 136 + cp] = (ushort_t)(pk >> 16);
      }
    }
    __syncthreads();
    #pragma unroll
    for (int ksl = 0; ksl < 4; ++ksl) {
      int ks = 4 * h + ksl;
      bf16x8 a = *(const bf16x8*)&u.qpb[(16 * wv + n15) * 136 + quad * 8 + 32 * ksl];
      aQ[ks] = a;
      #pragma unroll
      for (int j = 0; j < 8; ++j) {
        float qv = ubf((ushort_t)a[j]);
        qsum += qv;
        dq += qv * zv[quad * 8 + 32 * ks + j];
      }
    }
  }
  qsum += __shfl_xor(qsum, 16, 64); qsum += __shfl_xor(qsum, 32, 64);
  dq   += __shfl_xor(dq, 16, 64);   dq   += __shfl_xor(dq, 32, 64);
  if (quad == 0) { qsumS[16 * wv + n15] = qsum; dqS[16 * wv + n15] = dq; }

  __syncthreads();   // qpb reads done; c (As/Vt) region free

  // Vt fill (V is L3-warm after feat)
  #pragma unroll
  for (int p = 0; p < 16; ++p) {
    int idx = tid + p * 256;
    int t = idx >> 6, e = idx & 63;
    u.c.Vt[e * 72 + t] = bf16r(V[(size_t)bc * 4096 + idx]);
  }

  // ---- phase 2: 8 tiles: t=0..3 scores (As, rowsum); t=4..7 output ----
  float rs[4] = {0.f, 0.f, 0.f, 0.f};
  float dinv[4] = {0.f, 0.f, 0.f, 0.f};

  #pragma unroll
  for (int t = 0; t < 8; ++t) {
    asm volatile("s_waitcnt vmcnt(0)" ::: "memory");
    __builtin_amdgcn_s_barrier();
    if (t < 7) {
      const ushort_t* gt = (t < 3) ? (E + base + (size_t)(t + 1) * 4096)
                                   : (S + base + (size_t)(t - 3) * 4096);
      stage_tile(gt, &Bst[(t + 1) & 1][0], tid, wv);
    }

    bf16x8 bf[8];
    #pragma unroll
    for (int ks = 0; ks < 8; ++ks) {
      int rc = (4 * ks + quad) ^ (n15 & 7);
      bf[ks] = *(const bf16x8*)&Bst[t & 1][(n15 * 32 + rc) * 8];
    }
    f32x4 g = {0.f, 0.f, 0.f, 0.f};
    #pragma unroll
    for (int ks = 0; ks < 8; ++ks)
      g = __builtin_amdgcn_mfma_f32_16x16x32_bf16(aQ[ks], bf[ks], g, 0, 0, 0);

    if (t < 4) {
      int tc = t;
      #pragma unroll
      for (int rp = 0; rp < 2; ++rp) {
        int i0 = 16 * wv + quad * 4 + 2 * rp;
        int tt = 16 * tc + n15;
        float v0 = (tt <= i0)     ? (c1 * g[2 * rp]     + c0 * qsumS[i0])     : 0.f;
        float v1 = (tt <= i0 + 1) ? (c1 * g[2 * rp + 1] + c0 * qsumS[i0 + 1]) : 0.f;
        unsigned pk = cvtpk(v0, v1);
        u.c.As[i0 * 72 + tt] = (ushort_t)pk;
        u.c.As[(i0 + 1) * 72 + tt] = (ushort_t)(pk >> 16);
        rs[2 * rp] += v0;
        rs[2 * rp + 1] += v1;
      }
      if (t == 3) {
        #pragma unroll
        for (int r = 0; r < 4; ++r) {
          float v2 = rs[r];
          #pragma unroll
          for (int s = 1; s < 16; s <<= 1) v2 += __shfl_xor(v2, s, 64);
          int i = 16 * wv + quad * 4 + r;
          dinv[r] = 1.f / (dqS[i] + v2);
        }
      }
    } else {
      int ec = t - 4;
      f32x4 o = g;
      #pragma unroll
      for (int ks = 0; ks < 2; ++ks) {
        bf16x8 a2 = *(const bf16x8*)&u.c.As[(16 * wv + n15) * 72 + quad * 8 + 32 * ks];
        bf16x8 b2 = *(const bf16x8*)&u.c.Vt[(16 * ec + n15) * 72 + quad * 8 + 32 * ks];
        o = __builtin_amdgcn_mfma_f32_16x16x32_bf16(a2, b2, o, 0, 0, 0);
      }
      #pragma unroll
      for (int r = 0; r < 4; ++r) {
        int i = 16 * wv + quad * 4 + r;
        out[(size_t)bc * 4096 + (size_t)i * 64 + 16 * ec + n15] = o[r] * dinv[r];
      }
    }
  }
}

// ---------------------------------------------------------------------------
extern "C" void kernel_launch(void* const* d_in, const int* in_sizes, int n_in,
                              void* d_out, int out_size, void* d_ws, size_t ws_size,
                              hipStream_t stream)
{
  const float* q = (const float*)d_in[0];
  const float* k = (const float*)d_in[1];
  const float* v = (const float*)d_in[2];
  const float* P = (const float*)d_in[3];
  float* out = (float*)d_out;

  ushort_t* E   = (ushort_t*)d_ws;
  ushort_t* S   = E + 16777216;                 // SE then combined in place
  float*    zE  = (float*)(S + 16777216);       // 262144 floats
  float*    SV  = zE + 262144;                  // 65536 floats
  ushort_t* Phi = (ushort_t*)(SV + 65536);
  ushort_t* Plo = Phi + 16384;
  float*    bmax = (float*)(Plo + 16384);       // 1024 floats

  pconv_kernel<<<16, 256, 0, stream>>>(P, Phi, Plo);
  feat_mfma<<<1024, 256, 0, stream>>>(k, v, Phi, Plo, E, bmax, S, zE, SV);
  prefix_kernel<<<1040, 256, 0, stream>>>(S, zE, SV, bmax);
  fused_mfma<<<1024, 256, 0, stream>>>(q, Phi, Plo, E, bmax, zE, S, v, out);
}